// Round 6
// baseline (203.970 us; speedup 1.0000x reference)
//
#include <hip/hip_runtime.h>
#include <math.h>

// EfficientDet post-processing v16 (4 launches) — resubmission (round-5 bench
// failed on container acquisition, not kernel correctness).
// prep(transpose vec4)
// -> select(ONE block per class: u16-hist over all 110K keys -> pivot ->
//           collect<=2048 -> bitonic-2048 -> sorted class top-512 + decode blocks)
// -> nms(gather + named-scalar-register ballot IoU mask + early-exit greedy scan)
// -> final(hist-select top-100 over <=9000 kept entries).
// v16: class-level selection removes nms's 21-step resume-bitonic entirely;
// sort runs once in select, overlapped with decode blocks.

#define A_N   110484
#define C_N   90
#define KCAND 512
#define NBINS 8192        // 13-bit histogram bins (key >> 19)
#define KSH   19
#define MAXDET 100
#define IMG_F 768.0f
#define THRESH 0.05f
#define VTOT  (A_N / 4)                           // 27621 vec4 units per class
#define SL_CAP 2048                               // per-class candidate cap
#define KEEP_CAP 100
#define T_BLKS ((A_N + 63) / 64)                  // 1727 transpose blocks
#define SEL_T 512
#define D_BLKS ((A_N + SEL_T - 1) / SEL_T)        // 216 decode blocks
#define FCAP  512                                 // final collect capacity

typedef unsigned int u32;
typedef unsigned long long u64;

__device__ __forceinline__ u32 fkey(float f) {
    u32 u = __float_as_uint(f);
    return (u & 0x80000000u) ? ~u : (u | 0x80000000u);
}
__device__ __forceinline__ float unfkey(u32 k) {
    u32 u = (k & 0x80000000u) ? (k ^ 0x80000000u) : ~k;
    return __uint_as_float(u);
}
__device__ __forceinline__ u64 shflx64(u64 v, int m) {
    u32 lo = (u32)__shfl_xor((int)(u32)v, m, 64);
    u32 hi = (u32)__shfl_xor((int)(v >> 32), m, 64);
    return ((u64)hi << 32) | lo;
}

// ------- Stage 1: transpose (sigmoid->key, vec4 loads) -------
__global__ __launch_bounds__(256)
void prep_kernel(const float* __restrict__ cls,
                 u32* __restrict__ keysT) {
    __shared__ u32 tile[64 * 91];   // 23.3 KB, stride 91 (odd) = conflict-free
    const int a0 = blockIdx.x * 64;
    const int lim = min(64, A_N - a0);           // 64 or 20; lim*90 % 4 == 0
    const int n4 = (lim * C_N) >> 2;
    const float4* src4 = (const float4*)(cls + (size_t)a0 * C_N);
    for (int i4 = threadIdx.x; i4 < n4; i4 += 256) {
        float4 x4 = src4[i4];
        const u32 base = (u32)(4 * i4);
        float xs[4] = { x4.x, x4.y, x4.z, x4.w };
        #pragma unroll
        for (int k = 0; k < 4; ++k) {
            u32 i = base + k;
            u32 aa = i / C_N, c = i % C_N;
            float s = 1.0f / (1.0f + expf(-xs[k]));
            tile[aa * 91 + c] = fkey(s);
        }
    }
    __syncthreads();
    for (int j = threadIdx.x; j < C_N * 64; j += 256) {
        int c = j >> 6, aa = j & 63;
        if (aa < lim)
            keysT[(size_t)c * A_N + a0 + aa] = tile[aa * 91 + c];
    }
}

// ---- Stage 2: per-class exact sorted top-512 (+ decode blocks) ----
// One block per class: u16 hist over all 110484 keys, pivot, collect (<=2048),
// bitonic-2048 (8 waves x 4 regs), store sorted ranks 0..511.
__global__ __launch_bounds__(SEL_T)
void select_kernel(const u32* __restrict__ keysT,
                   const float* __restrict__ anchors,
                   const float* __restrict__ reg,
                   float4* __restrict__ boxes,
                   u64* __restrict__ candbuf) {
    __shared__ u32 hist[NBINS / 2];   // 16 KB, two u16 counters per word
    __shared__ u32 csum[SEL_T];       // 2 KB
    __shared__ u64 lbuf[SL_CAP];      // 16 KB
    __shared__ u32 sPv;
    __shared__ int lcnt;
    const int tid = threadIdx.x;

    if (blockIdx.x >= C_N) {    // decode blocks
        int a = (blockIdx.x - C_N) * SEL_T + tid;
        if (a < A_N) {
            float4 an = ((const float4*)anchors)[a];
            float4 dl = ((const float4*)reg)[a];
            float wa = an.z - an.x, ha = an.w - an.y;
            float cx = an.x + 0.5f * wa + dl.x * wa;
            float cy = an.y + 0.5f * ha + dl.y * ha;
            float w = expf(dl.z) * wa;
            float h = expf(dl.w) * ha;
            float4 o;
            o.x = fminf(fmaxf(cx - 0.5f * w, 0.0f), IMG_F);
            o.y = fminf(fmaxf(cy - 0.5f * h, 0.0f), IMG_F);
            o.z = fminf(fmaxf(cx + 0.5f * w, 0.0f), IMG_F);
            o.w = fminf(fmaxf(cy + 0.5f * h, 0.0f), IMG_F);
            boxes[a] = o;
        }
        return;
    }
    const int c = blockIdx.x;
    const uint4* kv = (const uint4*)(keysT + (size_t)c * A_N);

    for (int i = tid; i < NBINS / 2; i += SEL_T) hist[i] = 0;
    if (tid == 0) { sPv = 0; lcnt = 0; }
    __syncthreads();

    // --- pass 1: histogram (counts packed: even bin = low half, odd = high) ---
    #define HACC(K) do { \
        u32 b0 = (K).x >> KSH, b1 = (K).y >> KSH, b2 = (K).z >> KSH, b3 = (K).w >> KSH; \
        atomicAdd(&hist[b0 >> 1], 1u << ((b0 & 1) << 4)); \
        atomicAdd(&hist[b1 >> 1], 1u << ((b1 & 1) << 4)); \
        atomicAdd(&hist[b2 >> 1], 1u << ((b2 & 1) << 4)); \
        atomicAdd(&hist[b3 >> 1], 1u << ((b3 & 1) << 4)); } while (0)
    {
        int i = tid;
        for (; i + 3 * SEL_T < VTOT; i += 4 * SEL_T) {
            uint4 ka = kv[i], kb = kv[i + SEL_T], kc = kv[i + 2 * SEL_T], kd = kv[i + 3 * SEL_T];
            HACC(ka); HACC(kb); HACC(kc); HACC(kd);
        }
        for (; i < VTOT; i += SEL_T) { uint4 ka = kv[i]; HACC(ka); }
    }
    __syncthreads();

    // --- chunk sums (16 bins = 8 words per thread, descending), rotated reads ---
    u32 own = 0;
    {
        const int wb = (NBINS / 2) - 8 - 8 * tid;   // lowest word of my chunk
        const int g = (tid >> 2) & 7;               // rotation -> 2 lanes/bank
        #pragma unroll
        for (int jj = 0; jj < 8; ++jj) {
            u32 v = hist[wb + ((g + jj) & 7)];
            own += (v & 0xffffu) + (v >> 16);
        }
    }
    csum[tid] = own;
    __syncthreads();
    for (int off = 1; off < SEL_T; off <<= 1) {
        u32 v = csum[tid];
        u32 a = (tid >= off) ? csum[tid - off] : 0u;
        __syncthreads();
        csum[tid] = v + a;
        __syncthreads();
    }
    const u32 incl = csum[tid], excl = incl - own;
    if (excl < (u32)KCAND && incl >= (u32)KCAND) {
        u32 cum = excl;
        const int hb = NBINS - 1 - 16 * tid;
        for (int j = 0; j < 16; ++j) {
            int b = hb - j;
            u32 v = hist[b >> 1];
            u32 cnt = (b & 1) ? (v >> 16) : (v & 0xffffu);
            if (cum + cnt >= (u32)KCAND) { sPv = (u32)b; break; }
            cum += cnt;
        }
    }
    __syncthreads();
    const u32 P = sPv;

    // --- pass 2: collect candidates >= pivot bin (mostly L2 hits) ---
    #define CACC(K, BASE) do { \
        if (((K).x >> KSH) >= P) { int p = atomicAdd(&lcnt, 1); if (p < SL_CAP) lbuf[p] = (((u64)(~(K).x)) << 32) | (u32)(BASE); } \
        if (((K).y >> KSH) >= P) { int p = atomicAdd(&lcnt, 1); if (p < SL_CAP) lbuf[p] = (((u64)(~(K).y)) << 32) | (u32)((BASE) + 1); } \
        if (((K).z >> KSH) >= P) { int p = atomicAdd(&lcnt, 1); if (p < SL_CAP) lbuf[p] = (((u64)(~(K).z)) << 32) | (u32)((BASE) + 2); } \
        if (((K).w >> KSH) >= P) { int p = atomicAdd(&lcnt, 1); if (p < SL_CAP) lbuf[p] = (((u64)(~(K).w)) << 32) | (u32)((BASE) + 3); } } while (0)
    {
        int i = tid;
        for (; i + 3 * SEL_T < VTOT; i += 4 * SEL_T) {
            uint4 ka = kv[i], kb = kv[i + SEL_T], kc = kv[i + 2 * SEL_T], kd = kv[i + 3 * SEL_T];
            CACC(ka, 4 * i); CACC(kb, 4 * (i + SEL_T)); CACC(kc, 4 * (i + 2 * SEL_T)); CACC(kd, 4 * (i + 3 * SEL_T));
        }
        for (; i < VTOT; i += SEL_T) { uint4 ka = kv[i]; CACC(ka, 4 * i); }
    }
    __syncthreads();
    const int n = min(lcnt, SL_CAP);   // n >= 512 guaranteed by pivot
    for (int q = tid; q < SL_CAP; q += SEL_T) if (q >= n) lbuf[q] = ~0ULL;
    __syncthreads();

    // --- bitonic 2048 sort: 8 waves x (4 regs x 64 lanes) ---
    {
        const int l = tid & 63, w = tid >> 6;
        int ii[4]; u64 v[4];
        #pragma unroll
        for (int r = 0; r < 4; ++r) { ii[r] = 256 * w + 64 * r + l; v[r] = lbuf[ii[r]]; }
        __syncthreads();
        #pragma unroll
        for (u32 kk = 2; kk <= (u32)SL_CAP; kk <<= 1) {
            #pragma unroll
            for (u32 j = kk >> 1; j > 0; j >>= 1) {
                if (j >= 256) {
                    #pragma unroll
                    for (int r = 0; r < 4; ++r) lbuf[ii[r]] = v[r];
                    __syncthreads();
                    #pragma unroll
                    for (int r = 0; r < 4; ++r) {
                        u64 pv = lbuf[ii[r] ^ j];
                        bool up = ((ii[r] & kk) == 0);
                        bool m = (((ii[r] & j) == 0) == up);
                        v[r] = m ? (v[r] < pv ? v[r] : pv) : (v[r] > pv ? v[r] : pv);
                    }
                    __syncthreads();
                } else if (j >= 64) {
                    const int rx = (int)(j >> 6);   // 1 or 2
                    u64 nv[4];
                    #pragma unroll
                    for (int r = 0; r < 4; ++r) {
                        u64 pv = v[r ^ rx];
                        bool up = ((ii[r] & kk) == 0);
                        bool m = (((ii[r] & j) == 0) == up);
                        nv[r] = m ? (v[r] < pv ? v[r] : pv) : (v[r] > pv ? v[r] : pv);
                    }
                    #pragma unroll
                    for (int r = 0; r < 4; ++r) v[r] = nv[r];
                } else {
                    #pragma unroll
                    for (int r = 0; r < 4; ++r) {
                        u64 pv = shflx64(v[r], (int)j);
                        bool up = ((ii[r] & kk) == 0);
                        bool m = (((ii[r] & j) == 0) == up);
                        v[r] = m ? (v[r] < pv ? v[r] : pv) : (v[r] > pv ? v[r] : pv);
                    }
                }
            }
        }
        u64* cb = candbuf + (size_t)c * KCAND;
        #pragma unroll
        for (int r = 0; r < 4; ++r)
            if (ii[r] < KCAND) cb[ii[r]] = v[r];   // sorted ascending = best-first
    }
}

// ---- Stage 3: gather + ballot IoU mask + early-exit greedy scan + compact ----
__global__ __launch_bounds__(1024, 4)
void nms_kernel(const u64* __restrict__ candbuf,
                const float4* __restrict__ boxes,
                u32* __restrict__ keptbuf, u32* __restrict__ cnt2) {
    __shared__ u32 bmask[KCAND * 16];      // 32 KB
    __shared__ float4 bb4[KCAND];          // 8 KB
    __shared__ float sc[KCAND];            // 2 KB
    __shared__ u32 keepf[16], wbase[17];
    const int c = blockIdx.x, tid = threadIdx.x;
    const int l = tid & 63, w = tid >> 6;

    // gather sorted top-512 (sorted ascending by composite = best-first)
    if (tid < KCAND) {
        u64 e = candbuf[(size_t)c * KCAND + tid];
        sc[tid] = unfkey(~((u32)(e >> 32)));
        bb4[tid] = boxes[(u32)e];
    }
    if (tid < 16) keepf[tid] = 0;
    __syncthreads();

    // --- IoU mask: wave-per-row; column boxes in NAMED register scalars ---
    {
        const float4 cj0 = bb4[0 * 64 + l], cj1 = bb4[1 * 64 + l];
        const float4 cj2 = bb4[2 * 64 + l], cj3 = bb4[3 * 64 + l];
        const float4 cj4 = bb4[4 * 64 + l], cj5 = bb4[5 * 64 + l];
        const float4 cj6 = bb4[6 * 64 + l], cj7 = bb4[7 * 64 + l];
        const float aj0 = (cj0.z - cj0.x) * (cj0.w - cj0.y);
        const float aj1 = (cj1.z - cj1.x) * (cj1.w - cj1.y);
        const float aj2 = (cj2.z - cj2.x) * (cj2.w - cj2.y);
        const float aj3 = (cj3.z - cj3.x) * (cj3.w - cj3.y);
        const float aj4 = (cj4.z - cj4.x) * (cj4.w - cj4.y);
        const float aj5 = (cj5.z - cj5.x) * (cj5.w - cj5.y);
        const float aj6 = (cj6.z - cj6.x) * (cj6.w - cj6.y);
        const float aj7 = (cj7.z - cj7.x) * (cj7.w - cj7.y);

        #define QSTEP(QQ, CJ, AJ) do { \
            if (QQ >= q0) { \
                float xx1 = fmaxf(bi.x, (CJ).x), yy1 = fmaxf(bi.y, (CJ).y); \
                float xx2 = fminf(bi.z, (CJ).z), yy2 = fminf(bi.w, (CJ).w); \
                float inter = fmaxf(xx2 - xx1, 0.0f) * fmaxf(yy2 - yy1, 0.0f); \
                float uni = ai + (AJ) - inter + 1e-8f; \
                bool sup = ((QQ * 64 + l) > r) && (inter > 0.5f * uni); \
                u64 bal = __ballot(sup); \
                if (l == 0) *(u64*)(row + 2 * QQ) = bal; \
            } } while (0)

        for (int r = w; r < KCAND; r += 16) {
            const float4 bi = bb4[r];                 // broadcast read
            const float ai = (bi.z - bi.x) * (bi.w - bi.y);
            const int q0 = (r + 1) >> 6;              // wave-uniform
            u32* row = bmask + r * 16;
            if (l < 2 * q0) row[l] = 0;               // words below diagonal
            QSTEP(0, cj0, aj0); QSTEP(1, cj1, aj1);
            QSTEP(2, cj2, aj2); QSTEP(3, cj3, aj3);
            QSTEP(4, cj4, aj4); QSTEP(5, cj5, aj5);
            QSTEP(6, cj6, aj6); QSTEP(7, cj7, aj7);
        }
        #undef QSTEP
    }
    __syncthreads();

    // --- greedy scan, wave 0; register-pipelined rows + readlane chain ---
    if (tid < 64) {
        const int lw = tid & 15;
        u32 removed = 0, keepw = 0;
        u32 rA[8], rB[8]; float sA[8], sB[8];
        #pragma unroll
        for (int k = 0; k < 8; ++k) { rA[k] = bmask[k * 16 + lw]; sA[k] = sc[k]; }
        #pragma unroll 1
        for (int ch = 0; ch < 64; ch += 2) {
            const int tb1 = (ch + 1) * 8;
            #pragma unroll
            for (int k = 0; k < 8; ++k) { rB[k] = bmask[(tb1 + k) * 16 + lw]; sB[k] = sc[tb1 + k]; }
            {
                const int tb = ch * 8;
                #pragma unroll
                for (int k = 0; k < 8; ++k) {
                    const int t = tb + k;
                    u32 rw = (u32)__builtin_amdgcn_readlane((int)removed, t >> 5);
                    bool d = (sA[k] > THRESH) && (((rw >> (t & 31)) & 1u) == 0u);
                    removed |= d ? rA[k] : 0u;
                    keepw |= (d && (tid == (t >> 5))) ? (1u << (t & 31)) : 0u;
                }
            }
            const int tb2 = (ch + 2 < 64) ? (ch + 2) * 8 : 0;
            #pragma unroll
            for (int k = 0; k < 8; ++k) { rA[k] = bmask[(tb2 + k) * 16 + lw]; sA[k] = sc[tb2 + k]; }
            {
                #pragma unroll
                for (int k = 0; k < 8; ++k) {
                    const int t = tb1 + k;
                    u32 rw = (u32)__builtin_amdgcn_readlane((int)removed, t >> 5);
                    bool d = (sB[k] > THRESH) && (((rw >> (t & 31)) & 1u) == 0u);
                    removed |= d ? rB[k] : 0u;
                    keepw |= (d && (tid == (t >> 5))) ? (1u << (t & 31)) : 0u;
                }
            }
            // early exit: total kept so far (keepw nonzero only on lanes 0-15)
            u32 cnt = (u32)__popc(keepw);
            #pragma unroll
            for (int m = 32; m; m >>= 1) cnt += (u32)__shfl_xor((int)cnt, m, 64);
            if (cnt >= (u32)KEEP_CAP) break;
        }
        if (tid < 16) keepf[tid] = keepw;
    }
    __syncthreads();

    // --- compact kept (sorted order) to keptbuf, cap 100/class ---
    if (tid == 0) {
        u32 t = 0;
        for (int q = 0; q < 16; ++q) { wbase[q] = t; t += __popc(keepf[q]); }
        wbase[16] = t;
        cnt2[c] = (t < (u32)KEEP_CAP) ? t : (u32)KEEP_CAP;
    }
    __syncthreads();
    if (tid < KCAND) {
        u32 word = keepf[tid >> 5];
        u32 bit = (u32)tid & 31u;
        if ((word >> bit) & 1u) {
            u32 rank = wbase[tid >> 5] + __popc(word & ((1u << bit) - 1u));
            if (rank < (u32)KEEP_CAP) {
                float s = sc[tid];
                float4 b = bb4[tid];
                uint4 a2, b2;
                a2.x = ~fkey(s);
                a2.y = (u32)(c * KCAND + tid);
                a2.z = __float_as_uint(b.x);
                a2.w = __float_as_uint(b.y);
                b2.x = __float_as_uint(b.z);
                b2.y = __float_as_uint(b.w);
                b2.z = __float_as_uint(s);
                b2.w = 0u;
                uint4* e = (uint4*)(keptbuf + ((size_t)c * KEEP_CAP + rank) * 8);
                e[0] = a2; e[1] = b2;
            }
        }
    }
}

// ---- Stage 4: global top-100 via hist-select over <=9000 kept entries ----
__global__ __launch_bounds__(1024)
void final_kernel(const u32* __restrict__ keptbuf, const u32* __restrict__ cnt2,
                  float* __restrict__ out) {
    __shared__ u32 hist[NBINS];    // 32 KB
    __shared__ u32 csum[1024];     // 4 KB
    __shared__ u64 ebuf[FCAP];     // 4 KB keys
    __shared__ u32 eidx[FCAP];     // 2 KB payload (keptbuf entry index)
    __shared__ u32 scnt[C_N];
    __shared__ u32 sP;
    __shared__ int sN;
    const int tid = threadIdx.x;
    const int TOT = C_N * KEEP_CAP;   // 9000

    for (int i = tid; i < MAXDET * 7; i += 1024) out[i] = 0.0f;
    for (int i = tid; i < NBINS; i += 1024) hist[i] = 0;
    if (tid < C_N) scnt[tid] = cnt2[tid];
    if (tid == 0) { sN = 0; sP = NBINS - 1; }
    __syncthreads();

    // hist over composite high word (smaller = better -> ascending pivot)
    for (int i = tid; i < TOT; i += 1024) {
        u32 c = (u32)i / KEEP_CAP, pp = (u32)i % KEEP_CAP;
        if (pp < scnt[c]) {
            u32 khi = keptbuf[(size_t)i * 8];   // a.x = ~fkey(s)
            atomicAdd(&hist[khi >> KSH], 1u);
        }
    }
    __syncthreads();
    // ascending chunk sums (8 bins each) + Hillis-Steele scan
    u32 own = 0; const int lo = 8 * tid;
    #pragma unroll
    for (int j = 0; j < 8; ++j) own += hist[lo + j];
    csum[tid] = own;
    __syncthreads();
    for (int off = 1; off < 1024; off <<= 1) {
        u32 v = csum[tid];
        u32 a = (tid >= off) ? csum[tid - off] : 0u;
        __syncthreads();
        csum[tid] = v + a;
        __syncthreads();
    }
    const u32 incl = csum[tid], excl = incl - own;
    if (excl < (u32)MAXDET && incl >= (u32)MAXDET) {
        u32 cum = excl;
        for (int j = 0; j < 8; ++j) {
            u32 h = hist[lo + j];
            if (cum + h >= (u32)MAXDET) { sP = (u32)(lo + j); break; }
            cum += h;
        }
    }
    __syncthreads();
    const u32 P = sP;
    // collect entries with bin <= P
    for (int i = tid; i < TOT; i += 1024) {
        u32 c = (u32)i / KEEP_CAP, pp = (u32)i % KEEP_CAP;
        if (pp < scnt[c]) {
            const uint2 v2 = *((const uint2*)(keptbuf + (size_t)i * 8));
            if ((v2.x >> KSH) <= P) {
                int p = atomicAdd(&sN, 1);
                if (p < FCAP) {
                    ebuf[p] = ((u64)v2.x << 32) | v2.y;
                    eidx[p] = (u32)i;
                }
            }
        }
    }
    __syncthreads();
    const int n = min(sN, FCAP);
    u32 m = 128; while ((int)m < n) m <<= 1;   // 128..512, uniform
    for (int i = tid; i < (int)m; i += 1024) if (i >= n) ebuf[i] = ~0ULL;
    __syncthreads();
    // bitonic sort (key ebuf asc, payload eidx follows)
    for (u32 kk = 2; kk <= m; kk <<= 1) {
        for (u32 j = kk >> 1; j > 0; j >>= 1) {
            u32 i = (u32)tid;
            if (i < m) {
                u32 ixj = i ^ j;
                if (ixj > i) {
                    u64 x = ebuf[i], y = ebuf[ixj];
                    bool up = ((i & kk) == 0);
                    if (up ? (x > y) : (x < y)) {
                        ebuf[i] = y; ebuf[ixj] = x;
                        u32 t = eidx[i]; eidx[i] = eidx[ixj]; eidx[ixj] = t;
                    }
                }
            }
            __syncthreads();
        }
    }
    if (tid < MAXDET && tid < n) {
        u64 comp = ebuf[tid];
        if (comp != ~0ULL) {
            const uint4* e = (const uint4*)(keptbuf + (size_t)eidx[tid] * 8);
            uint4 a = e[0], b = e[1];
            float* o = out + tid * 7;
            o[0] = 0.0f;
            o[1] = __uint_as_float(a.z); o[2] = __uint_as_float(a.w);
            o[3] = __uint_as_float(b.x); o[4] = __uint_as_float(b.y);
            o[5] = __uint_as_float(b.z);
            o[6] = (float)(((u32)comp) >> 9);   // low word = c*512+pos -> class
        }
    }
}

extern "C" void kernel_launch(void* const* d_in, const int* in_sizes, int n_in,
                              void* d_out, int out_size, void* d_ws, size_t ws_size,
                              hipStream_t stream) {
    const float* reg     = (const float*)d_in[1];
    const float* cls     = (const float*)d_in[2];
    const float* anchors = (const float*)d_in[3];
    float* out = (float*)d_out;

    char* ws = (char*)d_ws;
    size_t off = 0;
    auto alloc = [&](size_t bytes) -> void* {
        void* p = ws + off;
        off = (off + bytes + 255) & ~(size_t)255;
        return p;
    };
    u32*    keysT   = (u32*)   alloc((size_t)C_N * A_N * sizeof(u32));          // 39.8 MB
    float4* boxes   = (float4*)alloc((size_t)A_N * sizeof(float4));             // 1.77 MB
    u64*    candbuf = (u64*)   alloc((size_t)C_N * KCAND * sizeof(u64));        // 368 KB
    u32*    keptbuf = (u32*)   alloc((size_t)C_N * KEEP_CAP * 8 * sizeof(u32)); // 288 KB
    u32*    cnt2    = (u32*)   alloc((size_t)C_N * sizeof(u32));
    (void)ws_size;

    prep_kernel<<<T_BLKS, 256, 0, stream>>>(cls, keysT);
    select_kernel<<<C_N + D_BLKS, SEL_T, 0, stream>>>(keysT, anchors, reg, boxes, candbuf);
    nms_kernel<<<C_N, 1024, 0, stream>>>(candbuf, boxes, keptbuf, cnt2);
    final_kernel<<<1, 1024, 0, stream>>>(keptbuf, cnt2, out);
}

// Round 7
// 190.115 us; speedup vs baseline: 1.0729x; 1.0729x over previous
//
#include <hip/hip_runtime.h>
#include <math.h>

// EfficientDet post-processing v17 (4 launches).
// prep(transpose vec4 + decode blocks)
// -> select(90 blocks x 1024 thr: u16-hist over all 110K keys, 8-wide loads ->
//           pivot -> collect<=2048 -> bitonic-2048 (16 waves x 2 regs) -> top-512)
// -> nms(gather + named-scalar-register ballot IoU mask + early-exit greedy scan)
// -> final(hist-select top-100 over <=9000 kept entries).
// v17: select latency fix: 1024 thr (16 waves), 8-wide MLP, decode moved to prep.

#define A_N   110484
#define C_N   90
#define KCAND 512
#define NBINS 8192        // 13-bit histogram bins (key >> 19)
#define KSH   19
#define MAXDET 100
#define IMG_F 768.0f
#define THRESH 0.05f
#define VTOT  (A_N / 4)                           // 27621 vec4 units per class
#define SL_CAP 2048                               // per-class candidate cap
#define KEEP_CAP 100
#define T_BLKS ((A_N + 63) / 64)                  // 1727 transpose blocks
#define PD_BLKS ((A_N + 255) / 256)               // 432 decode blocks (in prep)
#define SEL_T 1024
#define FCAP  512                                 // final collect capacity

typedef unsigned int u32;
typedef unsigned long long u64;

__device__ __forceinline__ u32 fkey(float f) {
    u32 u = __float_as_uint(f);
    return (u & 0x80000000u) ? ~u : (u | 0x80000000u);
}
__device__ __forceinline__ float unfkey(u32 k) {
    u32 u = (k & 0x80000000u) ? (k ^ 0x80000000u) : ~k;
    return __uint_as_float(u);
}
__device__ __forceinline__ u64 shflx64(u64 v, int m) {
    u32 lo = (u32)__shfl_xor((int)(u32)v, m, 64);
    u32 hi = (u32)__shfl_xor((int)(v >> 32), m, 64);
    return ((u64)hi << 32) | lo;
}

// ------- Stage 1: transpose (sigmoid->key, vec4 loads) + decode blocks -------
__global__ __launch_bounds__(256)
void prep_kernel(const float* __restrict__ cls,
                 const float* __restrict__ anchors,
                 const float* __restrict__ reg,
                 u32* __restrict__ keysT,
                 float4* __restrict__ boxes) {
    __shared__ u32 tile[64 * 91];   // 23.3 KB, stride 91 (odd) = conflict-free
    if (blockIdx.x >= T_BLKS) {     // decode blocks (independent of transpose)
        int a = (blockIdx.x - T_BLKS) * 256 + threadIdx.x;
        if (a < A_N) {
            float4 an = ((const float4*)anchors)[a];
            float4 dl = ((const float4*)reg)[a];
            float wa = an.z - an.x, ha = an.w - an.y;
            float cx = an.x + 0.5f * wa + dl.x * wa;
            float cy = an.y + 0.5f * ha + dl.y * ha;
            float w = expf(dl.z) * wa;
            float h = expf(dl.w) * ha;
            float4 o;
            o.x = fminf(fmaxf(cx - 0.5f * w, 0.0f), IMG_F);
            o.y = fminf(fmaxf(cy - 0.5f * h, 0.0f), IMG_F);
            o.z = fminf(fmaxf(cx + 0.5f * w, 0.0f), IMG_F);
            o.w = fminf(fmaxf(cy + 0.5f * h, 0.0f), IMG_F);
            boxes[a] = o;
        }
        return;
    }
    const int a0 = blockIdx.x * 64;
    const int lim = min(64, A_N - a0);           // 64 or 20; lim*90 % 4 == 0
    const int n4 = (lim * C_N) >> 2;
    const float4* src4 = (const float4*)(cls + (size_t)a0 * C_N);
    for (int i4 = threadIdx.x; i4 < n4; i4 += 256) {
        float4 x4 = src4[i4];
        const u32 base = (u32)(4 * i4);
        float xs[4] = { x4.x, x4.y, x4.z, x4.w };
        #pragma unroll
        for (int k = 0; k < 4; ++k) {
            u32 i = base + k;
            u32 aa = i / C_N, c = i % C_N;
            float s = 1.0f / (1.0f + expf(-xs[k]));
            tile[aa * 91 + c] = fkey(s);
        }
    }
    __syncthreads();
    for (int j = threadIdx.x; j < C_N * 64; j += 256) {
        int c = j >> 6, aa = j & 63;
        if (aa < lim)
            keysT[(size_t)c * A_N + a0 + aa] = tile[aa * 91 + c];
    }
}

// ---- Stage 2: per-class exact sorted top-512 ----
// 90 blocks x 1024 threads: u16 hist over all 110484 keys (8-wide loads),
// pivot, collect (<=2048), bitonic-2048 (16 waves x 2 regs), store ranks 0..511.
__global__ __launch_bounds__(SEL_T)
void select_kernel(const u32* __restrict__ keysT,
                   u64* __restrict__ candbuf) {
    __shared__ u32 hist[NBINS / 2];   // 16 KB, two u16 counters per word
    __shared__ u32 csum[SEL_T];       // 4 KB
    __shared__ u64 lbuf[SL_CAP];      // 16 KB
    __shared__ u32 sPv;
    __shared__ int lcnt;
    const int tid = threadIdx.x;
    const int c = blockIdx.x;
    const uint4* kv = (const uint4*)(keysT + (size_t)c * A_N);

    for (int i = tid; i < NBINS / 2; i += SEL_T) hist[i] = 0;
    if (tid == 0) { sPv = 0; lcnt = 0; }
    __syncthreads();

    // --- pass 1: histogram, 8-wide in-flight loads ---
    #define HACC(K) do { \
        u32 b0 = (K).x >> KSH, b1 = (K).y >> KSH, b2 = (K).z >> KSH, b3 = (K).w >> KSH; \
        atomicAdd(&hist[b0 >> 1], 1u << ((b0 & 1) << 4)); \
        atomicAdd(&hist[b1 >> 1], 1u << ((b1 & 1) << 4)); \
        atomicAdd(&hist[b2 >> 1], 1u << ((b2 & 1) << 4)); \
        atomicAdd(&hist[b3 >> 1], 1u << ((b3 & 1) << 4)); } while (0)
    {
        int i = tid;
        for (; i + 7 * SEL_T < VTOT; i += 8 * SEL_T) {
            uint4 k0 = kv[i], k1 = kv[i + SEL_T], k2 = kv[i + 2 * SEL_T], k3 = kv[i + 3 * SEL_T];
            uint4 k4 = kv[i + 4 * SEL_T], k5 = kv[i + 5 * SEL_T], k6 = kv[i + 6 * SEL_T], k7 = kv[i + 7 * SEL_T];
            HACC(k0); HACC(k1); HACC(k2); HACC(k3);
            HACC(k4); HACC(k5); HACC(k6); HACC(k7);
        }
        for (; i < VTOT; i += SEL_T) { uint4 ka = kv[i]; HACC(ka); }
    }
    __syncthreads();

    // --- chunk sums (8 bins = 4 words per thread, descending), rotated reads ---
    u32 own = 0;
    {
        const int wb = (NBINS / 2) - 4 - 4 * tid;   // lowest word of my chunk
        const int g = (tid >> 3) & 3;               // rotation -> 2 lanes/bank
        #pragma unroll
        for (int jj = 0; jj < 4; ++jj) {
            u32 v = hist[wb + ((g + jj) & 3)];
            own += (v & 0xffffu) + (v >> 16);
        }
    }
    csum[tid] = own;
    __syncthreads();
    for (int off = 1; off < SEL_T; off <<= 1) {
        u32 v = csum[tid];
        u32 a = (tid >= off) ? csum[tid - off] : 0u;
        __syncthreads();
        csum[tid] = v + a;
        __syncthreads();
    }
    const u32 incl = csum[tid], excl = incl - own;
    if (excl < (u32)KCAND && incl >= (u32)KCAND) {
        u32 cum = excl;
        const int hb = NBINS - 1 - 8 * tid;
        for (int j = 0; j < 8; ++j) {
            int b = hb - j;
            u32 v = hist[b >> 1];
            u32 cnt = (b & 1) ? (v >> 16) : (v & 0xffffu);
            if (cum + cnt >= (u32)KCAND) { sPv = (u32)b; break; }
            cum += cnt;
        }
    }
    __syncthreads();
    const u32 P = sPv;

    // --- pass 2: collect candidates >= pivot bin (L2-resident re-read) ---
    #define CACC(K, BASE) do { \
        if (((K).x >> KSH) >= P) { int p = atomicAdd(&lcnt, 1); if (p < SL_CAP) lbuf[p] = (((u64)(~(K).x)) << 32) | (u32)(BASE); } \
        if (((K).y >> KSH) >= P) { int p = atomicAdd(&lcnt, 1); if (p < SL_CAP) lbuf[p] = (((u64)(~(K).y)) << 32) | (u32)((BASE) + 1); } \
        if (((K).z >> KSH) >= P) { int p = atomicAdd(&lcnt, 1); if (p < SL_CAP) lbuf[p] = (((u64)(~(K).z)) << 32) | (u32)((BASE) + 2); } \
        if (((K).w >> KSH) >= P) { int p = atomicAdd(&lcnt, 1); if (p < SL_CAP) lbuf[p] = (((u64)(~(K).w)) << 32) | (u32)((BASE) + 3); } } while (0)
    {
        int i = tid;
        for (; i + 7 * SEL_T < VTOT; i += 8 * SEL_T) {
            uint4 k0 = kv[i], k1 = kv[i + SEL_T], k2 = kv[i + 2 * SEL_T], k3 = kv[i + 3 * SEL_T];
            uint4 k4 = kv[i + 4 * SEL_T], k5 = kv[i + 5 * SEL_T], k6 = kv[i + 6 * SEL_T], k7 = kv[i + 7 * SEL_T];
            CACC(k0, 4 * i); CACC(k1, 4 * (i + SEL_T)); CACC(k2, 4 * (i + 2 * SEL_T)); CACC(k3, 4 * (i + 3 * SEL_T));
            CACC(k4, 4 * (i + 4 * SEL_T)); CACC(k5, 4 * (i + 5 * SEL_T)); CACC(k6, 4 * (i + 6 * SEL_T)); CACC(k7, 4 * (i + 7 * SEL_T));
        }
        for (; i < VTOT; i += SEL_T) { uint4 ka = kv[i]; CACC(ka, 4 * i); }
    }
    __syncthreads();
    const int n = min(lcnt, SL_CAP);   // n >= 512 guaranteed by pivot
    for (int q = tid; q < SL_CAP; q += SEL_T) if (q >= n) lbuf[q] = ~0ULL;
    __syncthreads();

    // --- bitonic 2048 sort: 16 waves x (2 regs x 64 lanes) ---
    {
        const int l = tid & 63, w = tid >> 6;
        const int i0 = 128 * w + l, i1 = i0 + 64;
        u64 v0 = lbuf[i0], v1 = lbuf[i1];
        __syncthreads();
        #pragma unroll
        for (u32 kk = 2; kk <= (u32)SL_CAP; kk <<= 1) {
            #pragma unroll
            for (u32 j = kk >> 1; j > 0; j >>= 1) {
                if (j >= 128) {
                    lbuf[i0] = v0; lbuf[i1] = v1;
                    __syncthreads();
                    u64 w0 = lbuf[i0 ^ j], w1 = lbuf[i1 ^ j];
                    bool m0 = (((i0 & j) == 0) == ((i0 & kk) == 0));
                    bool m1 = (((i1 & j) == 0) == ((i1 & kk) == 0));
                    v0 = m0 ? (v0 < w0 ? v0 : w0) : (v0 > w0 ? v0 : w0);
                    v1 = m1 ? (v1 < w1 ? v1 : w1) : (v1 > w1 ? v1 : w1);
                    __syncthreads();
                } else if (j == 64) {
                    bool up = ((i0 & kk) == 0);
                    u64 mn = v0 < v1 ? v0 : v1, mx = v0 < v1 ? v1 : v0;
                    v0 = up ? mn : mx; v1 = up ? mx : mn;
                } else {
                    u64 w0 = shflx64(v0, (int)j), w1 = shflx64(v1, (int)j);
                    bool m0 = (((i0 & j) == 0) == ((i0 & kk) == 0));
                    bool m1 = (((i1 & j) == 0) == ((i1 & kk) == 0));
                    v0 = m0 ? (v0 < w0 ? v0 : w0) : (v0 > w0 ? v0 : w0);
                    v1 = m1 ? (v1 < w1 ? v1 : w1) : (v1 > w1 ? v1 : w1);
                }
            }
        }
        if (w < 4) {   // i0, i1 in [0, 512): ascending composite = best-first
            u64* cb = candbuf + (size_t)c * KCAND;
            cb[i0] = v0; cb[i1] = v1;
        }
    }
}

// ---- Stage 3: gather + ballot IoU mask + early-exit greedy scan + compact ----
__global__ __launch_bounds__(1024, 4)
void nms_kernel(const u64* __restrict__ candbuf,
                const float4* __restrict__ boxes,
                u32* __restrict__ keptbuf, u32* __restrict__ cnt2) {
    __shared__ u32 bmask[KCAND * 16];      // 32 KB
    __shared__ float4 bb4[KCAND];          // 8 KB
    __shared__ float sc[KCAND];            // 2 KB
    __shared__ u32 keepf[16], wbase[17];
    const int c = blockIdx.x, tid = threadIdx.x;
    const int l = tid & 63, w = tid >> 6;

    // gather sorted top-512 (sorted ascending by composite = best-first)
    if (tid < KCAND) {
        u64 e = candbuf[(size_t)c * KCAND + tid];
        sc[tid] = unfkey(~((u32)(e >> 32)));
        bb4[tid] = boxes[(u32)e];
    }
    if (tid < 16) keepf[tid] = 0;
    __syncthreads();

    // --- IoU mask: wave-per-row; column boxes in NAMED register scalars ---
    {
        const float4 cj0 = bb4[0 * 64 + l], cj1 = bb4[1 * 64 + l];
        const float4 cj2 = bb4[2 * 64 + l], cj3 = bb4[3 * 64 + l];
        const float4 cj4 = bb4[4 * 64 + l], cj5 = bb4[5 * 64 + l];
        const float4 cj6 = bb4[6 * 64 + l], cj7 = bb4[7 * 64 + l];
        const float aj0 = (cj0.z - cj0.x) * (cj0.w - cj0.y);
        const float aj1 = (cj1.z - cj1.x) * (cj1.w - cj1.y);
        const float aj2 = (cj2.z - cj2.x) * (cj2.w - cj2.y);
        const float aj3 = (cj3.z - cj3.x) * (cj3.w - cj3.y);
        const float aj4 = (cj4.z - cj4.x) * (cj4.w - cj4.y);
        const float aj5 = (cj5.z - cj5.x) * (cj5.w - cj5.y);
        const float aj6 = (cj6.z - cj6.x) * (cj6.w - cj6.y);
        const float aj7 = (cj7.z - cj7.x) * (cj7.w - cj7.y);

        #define QSTEP(QQ, CJ, AJ) do { \
            if (QQ >= q0) { \
                float xx1 = fmaxf(bi.x, (CJ).x), yy1 = fmaxf(bi.y, (CJ).y); \
                float xx2 = fminf(bi.z, (CJ).z), yy2 = fminf(bi.w, (CJ).w); \
                float inter = fmaxf(xx2 - xx1, 0.0f) * fmaxf(yy2 - yy1, 0.0f); \
                float uni = ai + (AJ) - inter + 1e-8f; \
                bool sup = ((QQ * 64 + l) > r) && (inter > 0.5f * uni); \
                u64 bal = __ballot(sup); \
                if (l == 0) *(u64*)(row + 2 * QQ) = bal; \
            } } while (0)

        for (int r = w; r < KCAND; r += 16) {
            const float4 bi = bb4[r];                 // broadcast read
            const float ai = (bi.z - bi.x) * (bi.w - bi.y);
            const int q0 = (r + 1) >> 6;              // wave-uniform
            u32* row = bmask + r * 16;
            if (l < 2 * q0) row[l] = 0;               // words below diagonal
            QSTEP(0, cj0, aj0); QSTEP(1, cj1, aj1);
            QSTEP(2, cj2, aj2); QSTEP(3, cj3, aj3);
            QSTEP(4, cj4, aj4); QSTEP(5, cj5, aj5);
            QSTEP(6, cj6, aj6); QSTEP(7, cj7, aj7);
        }
        #undef QSTEP
    }
    __syncthreads();

    // --- greedy scan, wave 0; register-pipelined rows + readlane chain ---
    if (tid < 64) {
        const int lw = tid & 15;
        u32 removed = 0, keepw = 0;
        u32 rA[8], rB[8]; float sA[8], sB[8];
        #pragma unroll
        for (int k = 0; k < 8; ++k) { rA[k] = bmask[k * 16 + lw]; sA[k] = sc[k]; }
        #pragma unroll 1
        for (int ch = 0; ch < 64; ch += 2) {
            const int tb1 = (ch + 1) * 8;
            #pragma unroll
            for (int k = 0; k < 8; ++k) { rB[k] = bmask[(tb1 + k) * 16 + lw]; sB[k] = sc[tb1 + k]; }
            {
                const int tb = ch * 8;
                #pragma unroll
                for (int k = 0; k < 8; ++k) {
                    const int t = tb + k;
                    u32 rw = (u32)__builtin_amdgcn_readlane((int)removed, t >> 5);
                    bool d = (sA[k] > THRESH) && (((rw >> (t & 31)) & 1u) == 0u);
                    removed |= d ? rA[k] : 0u;
                    keepw |= (d && (tid == (t >> 5))) ? (1u << (t & 31)) : 0u;
                }
            }
            const int tb2 = (ch + 2 < 64) ? (ch + 2) * 8 : 0;
            #pragma unroll
            for (int k = 0; k < 8; ++k) { rA[k] = bmask[(tb2 + k) * 16 + lw]; sA[k] = sc[tb2 + k]; }
            {
                #pragma unroll
                for (int k = 0; k < 8; ++k) {
                    const int t = tb1 + k;
                    u32 rw = (u32)__builtin_amdgcn_readlane((int)removed, t >> 5);
                    bool d = (sB[k] > THRESH) && (((rw >> (t & 31)) & 1u) == 0u);
                    removed |= d ? rB[k] : 0u;
                    keepw |= (d && (tid == (t >> 5))) ? (1u << (t & 31)) : 0u;
                }
            }
            // early exit: total kept so far (keepw nonzero only on lanes 0-15)
            u32 cnt = (u32)__popc(keepw);
            #pragma unroll
            for (int m = 32; m; m >>= 1) cnt += (u32)__shfl_xor((int)cnt, m, 64);
            if (cnt >= (u32)KEEP_CAP) break;
        }
        if (tid < 16) keepf[tid] = keepw;
    }
    __syncthreads();

    // --- compact kept (sorted order) to keptbuf, cap 100/class ---
    if (tid == 0) {
        u32 t = 0;
        for (int q = 0; q < 16; ++q) { wbase[q] = t; t += __popc(keepf[q]); }
        wbase[16] = t;
        cnt2[c] = (t < (u32)KEEP_CAP) ? t : (u32)KEEP_CAP;
    }
    __syncthreads();
    if (tid < KCAND) {
        u32 word = keepf[tid >> 5];
        u32 bit = (u32)tid & 31u;
        if ((word >> bit) & 1u) {
            u32 rank = wbase[tid >> 5] + __popc(word & ((1u << bit) - 1u));
            if (rank < (u32)KEEP_CAP) {
                float s = sc[tid];
                float4 b = bb4[tid];
                uint4 a2, b2;
                a2.x = ~fkey(s);
                a2.y = (u32)(c * KCAND + tid);
                a2.z = __float_as_uint(b.x);
                a2.w = __float_as_uint(b.y);
                b2.x = __float_as_uint(b.z);
                b2.y = __float_as_uint(b.w);
                b2.z = __float_as_uint(s);
                b2.w = 0u;
                uint4* e = (uint4*)(keptbuf + ((size_t)c * KEEP_CAP + rank) * 8);
                e[0] = a2; e[1] = b2;
            }
        }
    }
}

// ---- Stage 4: global top-100 via hist-select over <=9000 kept entries ----
__global__ __launch_bounds__(1024)
void final_kernel(const u32* __restrict__ keptbuf, const u32* __restrict__ cnt2,
                  float* __restrict__ out) {
    __shared__ u32 hist[NBINS];    // 32 KB
    __shared__ u32 csum[1024];     // 4 KB
    __shared__ u64 ebuf[FCAP];     // 4 KB keys
    __shared__ u32 eidx[FCAP];     // 2 KB payload (keptbuf entry index)
    __shared__ u32 scnt[C_N];
    __shared__ u32 sP;
    __shared__ int sN;
    const int tid = threadIdx.x;
    const int TOT = C_N * KEEP_CAP;   // 9000

    for (int i = tid; i < MAXDET * 7; i += 1024) out[i] = 0.0f;
    for (int i = tid; i < NBINS; i += 1024) hist[i] = 0;
    if (tid < C_N) scnt[tid] = cnt2[tid];
    if (tid == 0) { sN = 0; sP = NBINS - 1; }
    __syncthreads();

    // hist over composite high word (smaller = better -> ascending pivot)
    for (int i = tid; i < TOT; i += 1024) {
        u32 c = (u32)i / KEEP_CAP, pp = (u32)i % KEEP_CAP;
        if (pp < scnt[c]) {
            u32 khi = keptbuf[(size_t)i * 8];   // a.x = ~fkey(s)
            atomicAdd(&hist[khi >> KSH], 1u);
        }
    }
    __syncthreads();
    // ascending chunk sums (8 bins each) + Hillis-Steele scan
    u32 own = 0; const int lo = 8 * tid;
    #pragma unroll
    for (int j = 0; j < 8; ++j) own += hist[lo + j];
    csum[tid] = own;
    __syncthreads();
    for (int off = 1; off < 1024; off <<= 1) {
        u32 v = csum[tid];
        u32 a = (tid >= off) ? csum[tid - off] : 0u;
        __syncthreads();
        csum[tid] = v + a;
        __syncthreads();
    }
    const u32 incl = csum[tid], excl = incl - own;
    if (excl < (u32)MAXDET && incl >= (u32)MAXDET) {
        u32 cum = excl;
        for (int j = 0; j < 8; ++j) {
            u32 h = hist[lo + j];
            if (cum + h >= (u32)MAXDET) { sP = (u32)(lo + j); break; }
            cum += h;
        }
    }
    __syncthreads();
    const u32 P = sP;
    // collect entries with bin <= P
    for (int i = tid; i < TOT; i += 1024) {
        u32 c = (u32)i / KEEP_CAP, pp = (u32)i % KEEP_CAP;
        if (pp < scnt[c]) {
            const uint2 v2 = *((const uint2*)(keptbuf + (size_t)i * 8));
            if ((v2.x >> KSH) <= P) {
                int p = atomicAdd(&sN, 1);
                if (p < FCAP) {
                    ebuf[p] = ((u64)v2.x << 32) | v2.y;
                    eidx[p] = (u32)i;
                }
            }
        }
    }
    __syncthreads();
    const int n = min(sN, FCAP);
    u32 m = 128; while ((int)m < n) m <<= 1;   // 128..512, uniform
    for (int i = tid; i < (int)m; i += 1024) if (i >= n) ebuf[i] = ~0ULL;
    __syncthreads();
    // bitonic sort (key ebuf asc, payload eidx follows)
    for (u32 kk = 2; kk <= m; kk <<= 1) {
        for (u32 j = kk >> 1; j > 0; j >>= 1) {
            u32 i = (u32)tid;
            if (i < m) {
                u32 ixj = i ^ j;
                if (ixj > i) {
                    u64 x = ebuf[i], y = ebuf[ixj];
                    bool up = ((i & kk) == 0);
                    if (up ? (x > y) : (x < y)) {
                        ebuf[i] = y; ebuf[ixj] = x;
                        u32 t = eidx[i]; eidx[i] = eidx[ixj]; eidx[ixj] = t;
                    }
                }
            }
            __syncthreads();
        }
    }
    if (tid < MAXDET && tid < n) {
        u64 comp = ebuf[tid];
        if (comp != ~0ULL) {
            const uint4* e = (const uint4*)(keptbuf + (size_t)eidx[tid] * 8);
            uint4 a = e[0], b = e[1];
            float* o = out + tid * 7;
            o[0] = 0.0f;
            o[1] = __uint_as_float(a.z); o[2] = __uint_as_float(a.w);
            o[3] = __uint_as_float(b.x); o[4] = __uint_as_float(b.y);
            o[5] = __uint_as_float(b.z);
            o[6] = (float)(((u32)comp) >> 9);   // low word = c*512+pos -> class
        }
    }
}

extern "C" void kernel_launch(void* const* d_in, const int* in_sizes, int n_in,
                              void* d_out, int out_size, void* d_ws, size_t ws_size,
                              hipStream_t stream) {
    const float* reg     = (const float*)d_in[1];
    const float* cls     = (const float*)d_in[2];
    const float* anchors = (const float*)d_in[3];
    float* out = (float*)d_out;

    char* ws = (char*)d_ws;
    size_t off = 0;
    auto alloc = [&](size_t bytes) -> void* {
        void* p = ws + off;
        off = (off + bytes + 255) & ~(size_t)255;
        return p;
    };
    u32*    keysT   = (u32*)   alloc((size_t)C_N * A_N * sizeof(u32));          // 39.8 MB
    float4* boxes   = (float4*)alloc((size_t)A_N * sizeof(float4));             // 1.77 MB
    u64*    candbuf = (u64*)   alloc((size_t)C_N * KCAND * sizeof(u64));        // 368 KB
    u32*    keptbuf = (u32*)   alloc((size_t)C_N * KEEP_CAP * 8 * sizeof(u32)); // 288 KB
    u32*    cnt2    = (u32*)   alloc((size_t)C_N * sizeof(u32));
    (void)ws_size;

    prep_kernel<<<T_BLKS + PD_BLKS, 256, 0, stream>>>(cls, anchors, reg, keysT, boxes);
    select_kernel<<<C_N, SEL_T, 0, stream>>>(keysT, candbuf);
    nms_kernel<<<C_N, 1024, 0, stream>>>(candbuf, boxes, keptbuf, cnt2);
    final_kernel<<<1, 1024, 0, stream>>>(keptbuf, cnt2, out);
}

// Round 8
// 188.182 us; speedup vs baseline: 1.0839x; 1.0103x over previous
//
#include <hip/hip_runtime.h>
#include <math.h>

// EfficientDet post-processing v18 (3 launches).
// prep(transpose vec4 + decode blocks)
// -> selnms(90 blocks x 1024 thr, FUSED: u16-hist -> pivot -> collect<=2048 ->
//           bitonic-2048 -> top-512 in regs -> SoA -> ballot IoU mask ->
//           early-exit greedy scan -> compact; LDS phase-overlaid 44 KB)
// -> final(hist-select top-100 over <=9000 kept entries).
// v18: select->nms fusion removes candbuf round-trip + one launch gap.

#define A_N   110484
#define C_N   90
#define KCAND 512
#define NBINS 8192        // 13-bit histogram bins (key >> 19)
#define KSH   19
#define MAXDET 100
#define IMG_F 768.0f
#define THRESH 0.05f
#define VTOT  (A_N / 4)                           // 27621 vec4 units per class
#define SL_CAP 2048                               // per-class candidate cap
#define KEEP_CAP 100
#define T_BLKS ((A_N + 63) / 64)                  // 1727 transpose blocks
#define PD_BLKS ((A_N + 255) / 256)               // 432 decode blocks (in prep)
#define SEL_T 1024
#define FCAP  512                                 // final collect capacity

typedef unsigned int u32;
typedef unsigned long long u64;

__device__ __forceinline__ u32 fkey(float f) {
    u32 u = __float_as_uint(f);
    return (u & 0x80000000u) ? ~u : (u | 0x80000000u);
}
__device__ __forceinline__ float unfkey(u32 k) {
    u32 u = (k & 0x80000000u) ? (k ^ 0x80000000u) : ~k;
    return __uint_as_float(u);
}
__device__ __forceinline__ u64 shflx64(u64 v, int m) {
    u32 lo = (u32)__shfl_xor((int)(u32)v, m, 64);
    u32 hi = (u32)__shfl_xor((int)(v >> 32), m, 64);
    return ((u64)hi << 32) | lo;
}

// ------- Stage 1: transpose (sigmoid->key, vec4 loads) + decode blocks -------
__global__ __launch_bounds__(256)
void prep_kernel(const float* __restrict__ cls,
                 const float* __restrict__ anchors,
                 const float* __restrict__ reg,
                 u32* __restrict__ keysT,
                 float4* __restrict__ boxes) {
    __shared__ u32 tile[64 * 91];   // 23.3 KB, stride 91 (odd) = conflict-free
    if (blockIdx.x >= T_BLKS) {     // decode blocks (independent of transpose)
        int a = (blockIdx.x - T_BLKS) * 256 + threadIdx.x;
        if (a < A_N) {
            float4 an = ((const float4*)anchors)[a];
            float4 dl = ((const float4*)reg)[a];
            float wa = an.z - an.x, ha = an.w - an.y;
            float cx = an.x + 0.5f * wa + dl.x * wa;
            float cy = an.y + 0.5f * ha + dl.y * ha;
            float w = expf(dl.z) * wa;
            float h = expf(dl.w) * ha;
            float4 o;
            o.x = fminf(fmaxf(cx - 0.5f * w, 0.0f), IMG_F);
            o.y = fminf(fmaxf(cy - 0.5f * h, 0.0f), IMG_F);
            o.z = fminf(fmaxf(cx + 0.5f * w, 0.0f), IMG_F);
            o.w = fminf(fmaxf(cy + 0.5f * h, 0.0f), IMG_F);
            boxes[a] = o;
        }
        return;
    }
    const int a0 = blockIdx.x * 64;
    const int lim = min(64, A_N - a0);           // 64 or 20; lim*90 % 4 == 0
    const int n4 = (lim * C_N) >> 2;
    const float4* src4 = (const float4*)(cls + (size_t)a0 * C_N);
    for (int i4 = threadIdx.x; i4 < n4; i4 += 256) {
        float4 x4 = src4[i4];
        const u32 base = (u32)(4 * i4);
        float xs[4] = { x4.x, x4.y, x4.z, x4.w };
        #pragma unroll
        for (int k = 0; k < 4; ++k) {
            u32 i = base + k;
            u32 aa = i / C_N, c = i % C_N;
            float s = 1.0f / (1.0f + expf(-xs[k]));
            tile[aa * 91 + c] = fkey(s);
        }
    }
    __syncthreads();
    for (int j = threadIdx.x; j < C_N * 64; j += 256) {
        int c = j >> 6, aa = j & 63;
        if (aa < lim)
            keysT[(size_t)c * A_N + a0 + aa] = tile[aa * 91 + c];
    }
}

// ---- Stage 2: FUSED per-class select + NMS (90 blocks x 1024 threads) ----
// Phase A (select): u16 hist over 110484 keys (8-wide loads), pivot,
//   collect (<=2048), bitonic-2048 (16 waves x 2 regs) -> top-512 in registers.
// Phase B (nms): SoA -> register-column ballot IoU mask -> early-exit greedy
//   scan -> compact to keptbuf. LDS: one 44 KB arena, phase-overlaid.
__global__ __launch_bounds__(SEL_T, 4)
void selnms_kernel(const u32* __restrict__ keysT,
                   const float4* __restrict__ boxes,
                   u32* __restrict__ keptbuf, u32* __restrict__ cnt2) {
    // phase A layout: hist[4096]@0 (16K) | csum[1024]@4096 (4K) | lbuf[2048]@5120 (16K)
    // phase B layout: bb4[512]@0 (8K) | sc[512]@2048 (2K) | keepf@2560 wbase@2576 |
    //                 bmask[8192]@2608 (32K)  [bmask overlaps lbuf: safe after sort]
    __shared__ __align__(16) u32 smem[11264];   // 44 KB
    u32* hist = smem;                       // 4096 u32
    u32* csum = smem + 4096;                // 1024 u32
    u64* lbuf = (u64*)(smem + 5120);        // 2048 u64
    float4* bb4 = (float4*)smem;            // 512 float4
    float* sc = (float*)(smem + 2048);      // 512 float
    u32* keepf = smem + 2560;               // 16
    u32* wbase = smem + 2576;               // 17
    u32* bmask = smem + 2608;               // 512 rows x 16 words
    __shared__ u32 sPv;
    __shared__ int lcnt;
    const int tid = threadIdx.x;
    const int c = blockIdx.x;
    const int l = tid & 63, w = tid >> 6;
    const uint4* kv = (const uint4*)(keysT + (size_t)c * A_N);

    for (int i = tid; i < NBINS / 2; i += SEL_T) hist[i] = 0;
    if (tid == 0) { sPv = 0; lcnt = 0; }
    __syncthreads();

    // --- pass 1: histogram, 8-wide in-flight loads ---
    #define HACC(K) do { \
        u32 b0 = (K).x >> KSH, b1 = (K).y >> KSH, b2 = (K).z >> KSH, b3 = (K).w >> KSH; \
        atomicAdd(&hist[b0 >> 1], 1u << ((b0 & 1) << 4)); \
        atomicAdd(&hist[b1 >> 1], 1u << ((b1 & 1) << 4)); \
        atomicAdd(&hist[b2 >> 1], 1u << ((b2 & 1) << 4)); \
        atomicAdd(&hist[b3 >> 1], 1u << ((b3 & 1) << 4)); } while (0)
    {
        int i = tid;
        for (; i + 7 * SEL_T < VTOT; i += 8 * SEL_T) {
            uint4 k0 = kv[i], k1 = kv[i + SEL_T], k2 = kv[i + 2 * SEL_T], k3 = kv[i + 3 * SEL_T];
            uint4 k4 = kv[i + 4 * SEL_T], k5 = kv[i + 5 * SEL_T], k6 = kv[i + 6 * SEL_T], k7 = kv[i + 7 * SEL_T];
            HACC(k0); HACC(k1); HACC(k2); HACC(k3);
            HACC(k4); HACC(k5); HACC(k6); HACC(k7);
        }
        for (; i < VTOT; i += SEL_T) { uint4 ka = kv[i]; HACC(ka); }
    }
    __syncthreads();

    // --- chunk sums (8 bins = 4 words per thread, descending), rotated reads ---
    u32 own = 0;
    {
        const int wb = (NBINS / 2) - 4 - 4 * tid;   // lowest word of my chunk
        const int g = (tid >> 3) & 3;               // rotation -> 2 lanes/bank
        #pragma unroll
        for (int jj = 0; jj < 4; ++jj) {
            u32 v = hist[wb + ((g + jj) & 3)];
            own += (v & 0xffffu) + (v >> 16);
        }
    }
    csum[tid] = own;
    __syncthreads();
    for (int off = 1; off < SEL_T; off <<= 1) {
        u32 v = csum[tid];
        u32 a = (tid >= off) ? csum[tid - off] : 0u;
        __syncthreads();
        csum[tid] = v + a;
        __syncthreads();
    }
    const u32 incl = csum[tid], excl = incl - own;
    if (excl < (u32)KCAND && incl >= (u32)KCAND) {
        u32 cum = excl;
        const int hb = NBINS - 1 - 8 * tid;
        for (int j = 0; j < 8; ++j) {
            int b = hb - j;
            u32 v = hist[b >> 1];
            u32 cnt = (b & 1) ? (v >> 16) : (v & 0xffffu);
            if (cum + cnt >= (u32)KCAND) { sPv = (u32)b; break; }
            cum += cnt;
        }
    }
    __syncthreads();
    const u32 P = sPv;

    // --- pass 2: collect candidates >= pivot bin (L2-resident re-read) ---
    #define CACC(K, BASE) do { \
        if (((K).x >> KSH) >= P) { int p = atomicAdd(&lcnt, 1); if (p < SL_CAP) lbuf[p] = (((u64)(~(K).x)) << 32) | (u32)(BASE); } \
        if (((K).y >> KSH) >= P) { int p = atomicAdd(&lcnt, 1); if (p < SL_CAP) lbuf[p] = (((u64)(~(K).y)) << 32) | (u32)((BASE) + 1); } \
        if (((K).z >> KSH) >= P) { int p = atomicAdd(&lcnt, 1); if (p < SL_CAP) lbuf[p] = (((u64)(~(K).z)) << 32) | (u32)((BASE) + 2); } \
        if (((K).w >> KSH) >= P) { int p = atomicAdd(&lcnt, 1); if (p < SL_CAP) lbuf[p] = (((u64)(~(K).w)) << 32) | (u32)((BASE) + 3); } } while (0)
    {
        int i = tid;
        for (; i + 7 * SEL_T < VTOT; i += 8 * SEL_T) {
            uint4 k0 = kv[i], k1 = kv[i + SEL_T], k2 = kv[i + 2 * SEL_T], k3 = kv[i + 3 * SEL_T];
            uint4 k4 = kv[i + 4 * SEL_T], k5 = kv[i + 5 * SEL_T], k6 = kv[i + 6 * SEL_T], k7 = kv[i + 7 * SEL_T];
            CACC(k0, 4 * i); CACC(k1, 4 * (i + SEL_T)); CACC(k2, 4 * (i + 2 * SEL_T)); CACC(k3, 4 * (i + 3 * SEL_T));
            CACC(k4, 4 * (i + 4 * SEL_T)); CACC(k5, 4 * (i + 5 * SEL_T)); CACC(k6, 4 * (i + 6 * SEL_T)); CACC(k7, 4 * (i + 7 * SEL_T));
        }
        for (; i < VTOT; i += SEL_T) { uint4 ka = kv[i]; CACC(ka, 4 * i); }
    }
    __syncthreads();
    const int n = min(lcnt, SL_CAP);   // n >= 512 guaranteed by pivot
    for (int q = tid; q < SL_CAP; q += SEL_T) if (q >= n) lbuf[q] = ~0ULL;
    __syncthreads();

    // --- bitonic 2048 sort: 16 waves x (2 regs x 64 lanes) ---
    const int i0 = 128 * w + l, i1 = i0 + 64;
    u64 v0, v1;
    {
        v0 = lbuf[i0]; v1 = lbuf[i1];
        __syncthreads();
        #pragma unroll
        for (u32 kk = 2; kk <= (u32)SL_CAP; kk <<= 1) {
            #pragma unroll
            for (u32 j = kk >> 1; j > 0; j >>= 1) {
                if (j >= 128) {
                    lbuf[i0] = v0; lbuf[i1] = v1;
                    __syncthreads();
                    u64 w0 = lbuf[i0 ^ j], w1 = lbuf[i1 ^ j];
                    bool m0 = (((i0 & j) == 0) == ((i0 & kk) == 0));
                    bool m1 = (((i1 & j) == 0) == ((i1 & kk) == 0));
                    v0 = m0 ? (v0 < w0 ? v0 : w0) : (v0 > w0 ? v0 : w0);
                    v1 = m1 ? (v1 < w1 ? v1 : w1) : (v1 > w1 ? v1 : w1);
                    __syncthreads();
                } else if (j == 64) {
                    bool up = ((i0 & kk) == 0);
                    u64 mn = v0 < v1 ? v0 : v1, mx = v0 < v1 ? v1 : v0;
                    v0 = up ? mn : mx; v1 = up ? mx : mn;
                } else {
                    u64 w0 = shflx64(v0, (int)j), w1 = shflx64(v1, (int)j);
                    bool m0 = (((i0 & j) == 0) == ((i0 & kk) == 0));
                    bool m1 = (((i1 & j) == 0) == ((i1 & kk) == 0));
                    v0 = m0 ? (v0 < w0 ? v0 : w0) : (v0 > w0 ? v0 : w0);
                    v1 = m1 ? (v1 < w1 ? v1 : w1) : (v1 > w1 ? v1 : w1);
                }
            }
        }
    }
    __syncthreads();   // sort values now in registers; lbuf region reusable

    // --- phase B: top-512 -> SoA (ranks i0,i1 < 512 live in waves w<4) ---
    if (w < 4) {
        sc[i0] = unfkey(~((u32)(v0 >> 32)));
        sc[i1] = unfkey(~((u32)(v1 >> 32)));
        bb4[i0] = boxes[(u32)v0];
        bb4[i1] = boxes[(u32)v1];
    }
    if (tid < 16) keepf[tid] = 0;
    __syncthreads();

    // --- IoU mask: wave-per-row; column boxes in NAMED register scalars ---
    {
        const float4 cj0 = bb4[0 * 64 + l], cj1 = bb4[1 * 64 + l];
        const float4 cj2 = bb4[2 * 64 + l], cj3 = bb4[3 * 64 + l];
        const float4 cj4 = bb4[4 * 64 + l], cj5 = bb4[5 * 64 + l];
        const float4 cj6 = bb4[6 * 64 + l], cj7 = bb4[7 * 64 + l];
        const float aj0 = (cj0.z - cj0.x) * (cj0.w - cj0.y);
        const float aj1 = (cj1.z - cj1.x) * (cj1.w - cj1.y);
        const float aj2 = (cj2.z - cj2.x) * (cj2.w - cj2.y);
        const float aj3 = (cj3.z - cj3.x) * (cj3.w - cj3.y);
        const float aj4 = (cj4.z - cj4.x) * (cj4.w - cj4.y);
        const float aj5 = (cj5.z - cj5.x) * (cj5.w - cj5.y);
        const float aj6 = (cj6.z - cj6.x) * (cj6.w - cj6.y);
        const float aj7 = (cj7.z - cj7.x) * (cj7.w - cj7.y);

        #define QSTEP(QQ, CJ, AJ) do { \
            if (QQ >= q0) { \
                float xx1 = fmaxf(bi.x, (CJ).x), yy1 = fmaxf(bi.y, (CJ).y); \
                float xx2 = fminf(bi.z, (CJ).z), yy2 = fminf(bi.w, (CJ).w); \
                float inter = fmaxf(xx2 - xx1, 0.0f) * fmaxf(yy2 - yy1, 0.0f); \
                float uni = ai + (AJ) - inter + 1e-8f; \
                bool sup = ((QQ * 64 + l) > r) && (inter > 0.5f * uni); \
                u64 bal = __ballot(sup); \
                if (l == 0) *(u64*)(row + 2 * QQ) = bal; \
            } } while (0)

        for (int r = w; r < KCAND; r += 16) {
            const float4 bi = bb4[r];                 // broadcast read
            const float ai = (bi.z - bi.x) * (bi.w - bi.y);
            const int q0 = (r + 1) >> 6;              // wave-uniform
            u32* row = bmask + r * 16;
            if (l < 2 * q0) row[l] = 0;               // words below diagonal
            QSTEP(0, cj0, aj0); QSTEP(1, cj1, aj1);
            QSTEP(2, cj2, aj2); QSTEP(3, cj3, aj3);
            QSTEP(4, cj4, aj4); QSTEP(5, cj5, aj5);
            QSTEP(6, cj6, aj6); QSTEP(7, cj7, aj7);
        }
        #undef QSTEP
    }
    __syncthreads();

    // --- greedy scan, wave 0; register-pipelined rows + readlane chain ---
    if (tid < 64) {
        const int lw = tid & 15;
        u32 removed = 0, keepw = 0;
        u32 rA[8], rB[8]; float sA[8], sB[8];
        #pragma unroll
        for (int k = 0; k < 8; ++k) { rA[k] = bmask[k * 16 + lw]; sA[k] = sc[k]; }
        #pragma unroll 1
        for (int ch = 0; ch < 64; ch += 2) {
            const int tb1 = (ch + 1) * 8;
            #pragma unroll
            for (int k = 0; k < 8; ++k) { rB[k] = bmask[(tb1 + k) * 16 + lw]; sB[k] = sc[tb1 + k]; }
            {
                const int tb = ch * 8;
                #pragma unroll
                for (int k = 0; k < 8; ++k) {
                    const int t = tb + k;
                    u32 rw = (u32)__builtin_amdgcn_readlane((int)removed, t >> 5);
                    bool d = (sA[k] > THRESH) && (((rw >> (t & 31)) & 1u) == 0u);
                    removed |= d ? rA[k] : 0u;
                    keepw |= (d && (tid == (t >> 5))) ? (1u << (t & 31)) : 0u;
                }
            }
            const int tb2 = (ch + 2 < 64) ? (ch + 2) * 8 : 0;
            #pragma unroll
            for (int k = 0; k < 8; ++k) { rA[k] = bmask[(tb2 + k) * 16 + lw]; sA[k] = sc[tb2 + k]; }
            {
                #pragma unroll
                for (int k = 0; k < 8; ++k) {
                    const int t = tb1 + k;
                    u32 rw = (u32)__builtin_amdgcn_readlane((int)removed, t >> 5);
                    bool d = (sB[k] > THRESH) && (((rw >> (t & 31)) & 1u) == 0u);
                    removed |= d ? rB[k] : 0u;
                    keepw |= (d && (tid == (t >> 5))) ? (1u << (t & 31)) : 0u;
                }
            }
            // early exit: total kept so far (keepw nonzero only on lanes 0-15)
            u32 cnt = (u32)__popc(keepw);
            #pragma unroll
            for (int m = 32; m; m >>= 1) cnt += (u32)__shfl_xor((int)cnt, m, 64);
            if (cnt >= (u32)KEEP_CAP) break;
        }
        if (tid < 16) keepf[tid] = keepw;
    }
    __syncthreads();

    // --- compact kept (sorted order) to keptbuf, cap 100/class ---
    if (tid == 0) {
        u32 t = 0;
        for (int q = 0; q < 16; ++q) { wbase[q] = t; t += __popc(keepf[q]); }
        wbase[16] = t;
        cnt2[c] = (t < (u32)KEEP_CAP) ? t : (u32)KEEP_CAP;
    }
    __syncthreads();
    if (tid < KCAND) {
        u32 word = keepf[tid >> 5];
        u32 bit = (u32)tid & 31u;
        if ((word >> bit) & 1u) {
            u32 rank = wbase[tid >> 5] + __popc(word & ((1u << bit) - 1u));
            if (rank < (u32)KEEP_CAP) {
                float s = sc[tid];
                float4 b = bb4[tid];
                uint4 a2, b2;
                a2.x = ~fkey(s);
                a2.y = (u32)(c * KCAND + tid);
                a2.z = __float_as_uint(b.x);
                a2.w = __float_as_uint(b.y);
                b2.x = __float_as_uint(b.z);
                b2.y = __float_as_uint(b.w);
                b2.z = __float_as_uint(s);
                b2.w = 0u;
                uint4* e = (uint4*)(keptbuf + ((size_t)c * KEEP_CAP + rank) * 8);
                e[0] = a2; e[1] = b2;
            }
        }
    }
}

// ---- Stage 3: global top-100 via hist-select over <=9000 kept entries ----
__global__ __launch_bounds__(1024)
void final_kernel(const u32* __restrict__ keptbuf, const u32* __restrict__ cnt2,
                  float* __restrict__ out) {
    __shared__ u32 hist[NBINS];    // 32 KB
    __shared__ u32 csum[1024];     // 4 KB
    __shared__ u64 ebuf[FCAP];     // 4 KB keys
    __shared__ u32 eidx[FCAP];     // 2 KB payload (keptbuf entry index)
    __shared__ u32 scnt[C_N];
    __shared__ u32 sP;
    __shared__ int sN;
    const int tid = threadIdx.x;
    const int TOT = C_N * KEEP_CAP;   // 9000

    for (int i = tid; i < MAXDET * 7; i += 1024) out[i] = 0.0f;
    for (int i = tid; i < NBINS; i += 1024) hist[i] = 0;
    if (tid < C_N) scnt[tid] = cnt2[tid];
    if (tid == 0) { sN = 0; sP = NBINS - 1; }
    __syncthreads();

    // hist over composite high word (smaller = better -> ascending pivot)
    for (int i = tid; i < TOT; i += 1024) {
        u32 c = (u32)i / KEEP_CAP, pp = (u32)i % KEEP_CAP;
        if (pp < scnt[c]) {
            u32 khi = keptbuf[(size_t)i * 8];   // a.x = ~fkey(s)
            atomicAdd(&hist[khi >> KSH], 1u);
        }
    }
    __syncthreads();
    // ascending chunk sums (8 bins each) + Hillis-Steele scan
    u32 own = 0; const int lo = 8 * tid;
    #pragma unroll
    for (int j = 0; j < 8; ++j) own += hist[lo + j];
    csum[tid] = own;
    __syncthreads();
    for (int off = 1; off < 1024; off <<= 1) {
        u32 v = csum[tid];
        u32 a = (tid >= off) ? csum[tid - off] : 0u;
        __syncthreads();
        csum[tid] = v + a;
        __syncthreads();
    }
    const u32 incl = csum[tid], excl = incl - own;
    if (excl < (u32)MAXDET && incl >= (u32)MAXDET) {
        u32 cum = excl;
        for (int j = 0; j < 8; ++j) {
            u32 h = hist[lo + j];
            if (cum + h >= (u32)MAXDET) { sP = (u32)(lo + j); break; }
            cum += h;
        }
    }
    __syncthreads();
    const u32 P = sP;
    // collect entries with bin <= P
    for (int i = tid; i < TOT; i += 1024) {
        u32 c = (u32)i / KEEP_CAP, pp = (u32)i % KEEP_CAP;
        if (pp < scnt[c]) {
            const uint2 v2 = *((const uint2*)(keptbuf + (size_t)i * 8));
            if ((v2.x >> KSH) <= P) {
                int p = atomicAdd(&sN, 1);
                if (p < FCAP) {
                    ebuf[p] = ((u64)v2.x << 32) | v2.y;
                    eidx[p] = (u32)i;
                }
            }
        }
    }
    __syncthreads();
    const int n = min(sN, FCAP);
    u32 m = 128; while ((int)m < n) m <<= 1;   // 128..512, uniform
    for (int i = tid; i < (int)m; i += 1024) if (i >= n) ebuf[i] = ~0ULL;
    __syncthreads();
    // bitonic sort (key ebuf asc, payload eidx follows)
    for (u32 kk = 2; kk <= m; kk <<= 1) {
        for (u32 j = kk >> 1; j > 0; j >>= 1) {
            u32 i = (u32)tid;
            if (i < m) {
                u32 ixj = i ^ j;
                if (ixj > i) {
                    u64 x = ebuf[i], y = ebuf[ixj];
                    bool up = ((i & kk) == 0);
                    if (up ? (x > y) : (x < y)) {
                        ebuf[i] = y; ebuf[ixj] = x;
                        u32 t = eidx[i]; eidx[i] = eidx[ixj]; eidx[ixj] = t;
                    }
                }
            }
            __syncthreads();
        }
    }
    if (tid < MAXDET && tid < n) {
        u64 comp = ebuf[tid];
        if (comp != ~0ULL) {
            const uint4* e = (const uint4*)(keptbuf + (size_t)eidx[tid] * 8);
            uint4 a = e[0], b = e[1];
            float* o = out + tid * 7;
            o[0] = 0.0f;
            o[1] = __uint_as_float(a.z); o[2] = __uint_as_float(a.w);
            o[3] = __uint_as_float(b.x); o[4] = __uint_as_float(b.y);
            o[5] = __uint_as_float(b.z);
            o[6] = (float)(((u32)comp) >> 9);   // low word = c*512+pos -> class
        }
    }
}

extern "C" void kernel_launch(void* const* d_in, const int* in_sizes, int n_in,
                              void* d_out, int out_size, void* d_ws, size_t ws_size,
                              hipStream_t stream) {
    const float* reg     = (const float*)d_in[1];
    const float* cls     = (const float*)d_in[2];
    const float* anchors = (const float*)d_in[3];
    float* out = (float*)d_out;

    char* ws = (char*)d_ws;
    size_t off = 0;
    auto alloc = [&](size_t bytes) -> void* {
        void* p = ws + off;
        off = (off + bytes + 255) & ~(size_t)255;
        return p;
    };
    u32*    keysT   = (u32*)   alloc((size_t)C_N * A_N * sizeof(u32));          // 39.8 MB
    float4* boxes   = (float4*)alloc((size_t)A_N * sizeof(float4));             // 1.77 MB
    u32*    keptbuf = (u32*)   alloc((size_t)C_N * KEEP_CAP * 8 * sizeof(u32)); // 288 KB
    u32*    cnt2    = (u32*)   alloc((size_t)C_N * sizeof(u32));
    (void)ws_size;

    prep_kernel<<<T_BLKS + PD_BLKS, 256, 0, stream>>>(cls, anchors, reg, keysT, boxes);
    selnms_kernel<<<C_N, SEL_T, 0, stream>>>(keysT, boxes, keptbuf, cnt2);
    final_kernel<<<1, 1024, 0, stream>>>(keptbuf, cnt2, out);
}